// Round 1
// baseline (220.834 us; speedup 1.0000x reference)
//
#include <hip/hip_runtime.h>
#include <math.h>

#define ALPHA 0.2f

static constexpr int NN = 8, HH = 64, WW = 64, TT = 32, VV = 32, FF = 32;

// workspace layout (float offsets)
static constexpr size_t WS_ADJ = 0;      // 1024: adj_n [i][j]
static constexpr size_t WS_WA1 = 1024;   // 32: W_map @ a1
static constexpr size_t WS_WA2 = 1056;   // 32: W_map @ a2
static constexpr size_t WS_C12 = 1088;   // 2: b.a1, b.a2
static constexpr size_t WS_S1  = 2048;                         // N*H*W*V = 1048576, [n][h][w][i]
static constexpr size_t WS_S2  = WS_S1 + (size_t)NN*HH*WW*VV;  // same
static constexpr size_t WS_DEN = WS_S2 + (size_t)NN*HH*WW*VV;  // N*H*V*V = 524288, [n][h][i][j] = 1/denom

__global__ __launch_bounds__(1024) void k0_prep(const float* __restrict__ W_map,
    const float* __restrict__ b_map, const float* __restrict__ a_attn,
    const float* __restrict__ B_adj, float* __restrict__ ws)
{
    __shared__ float lds[1024];
    __shared__ float d12[32];
    int tid = threadIdx.x;
    int i = tid >> 5, j = tid & 31;
    float a = B_adj[tid] + (i == j ? 1.0f : 0.0f);
    lds[tid] = a; __syncthreads();
    for (int s = 512; s > 0; s >>= 1) { if (tid < s) lds[tid] = fmaxf(lds[tid], lds[tid + s]); __syncthreads(); }
    float mx = lds[0]; __syncthreads();
    lds[tid] = a; __syncthreads();
    for (int s = 512; s > 0; s >>= 1) { if (tid < s) lds[tid] = fminf(lds[tid], lds[tid + s]); __syncthreads(); }
    float mn = lds[0]; __syncthreads();
    float nrm = (a - mn) / (mx - mn);
    lds[tid] = nrm; __syncthreads();
    if (tid < 32) {
        float s = 0.f;
        for (int jj = 0; jj < 32; ++jj) s += lds[tid * 32 + jj];
        d12[tid] = 1.0f / sqrtf(s);
    }
    __syncthreads();
    ws[WS_ADJ + tid] = d12[i] * nrm * d12[j];
    if (tid < 32) {
        float w1 = 0.f, w2 = 0.f;
        for (int f = 0; f < 32; ++f) {
            w1 += W_map[tid * 32 + f] * a_attn[f];
            w2 += W_map[tid * 32 + f] * a_attn[32 + f];
        }
        ws[WS_WA1 + tid] = w1; ws[WS_WA2 + tid] = w2;
    }
    if (tid == 0) {
        float c1 = 0.f, c2 = 0.f;
        for (int f = 0; f < 32; ++f) { c1 += b_map[f] * a_attn[f]; c2 += b_map[f] * a_attn[32 + f]; }
        ws[WS_C12] = c1; ws[WS_C12 + 1] = c2;
    }
}

// s1[n,i,h,w] = sum_t h[n,h,w,t,i] * wa1[t] + c1   stored [n][h][w][i]
__global__ __launch_bounds__(256) void k1_scores(const float* __restrict__ hin, float* __restrict__ ws)
{
    __shared__ float lwa1[32], lwa2[32];
    int tid = threadIdx.x;
    if (tid < 32) lwa1[tid] = ws[WS_WA1 + tid];
    else if (tid < 64) lwa2[tid - 32] = ws[WS_WA2 + (tid - 32)];
    __syncthreads();
    float c1 = ws[WS_C12], c2 = ws[WS_C12 + 1];
    int g = tid >> 5, lane = tid & 31;
    long site = (long)blockIdx.x * 8 + g;      // (n*64+h)*64 + w
    const float* hp = hin + site * 1024;       // [t][v]
    float a1 = c1, a2 = c2;
#pragma unroll
    for (int t = 0; t < 32; ++t) {
        float x = hp[t * 32 + lane];
        a1 = fmaf(x, lwa1[t], a1);
        a2 = fmaf(x, lwa2[t], a2);
    }
    ws[WS_S1 + site * 32 + lane] = a1;
    ws[WS_S2 + site * 32 + lane] = a2;
}

// rden[n,h,i,j] = 1 / sum_w exp(lrelu(s1[i,w]+s2[j,w]))
__global__ __launch_bounds__(1024) void k2_denom(float* __restrict__ ws)
{
    __shared__ float ls1[2048], ls2[2048];  // [w][i]
    int tid = threadIdx.x;
    long nh = blockIdx.x;
    const float* s1 = ws + WS_S1 + nh * 2048;
    const float* s2 = ws + WS_S2 + nh * 2048;
    ls1[tid] = s1[tid]; ls1[tid + 1024] = s1[tid + 1024];
    ls2[tid] = s2[tid]; ls2[tid + 1024] = s2[tid + 1024];
    __syncthreads();
    int i = tid >> 5, j = tid & 31;
    float sum = 0.f;
#pragma unroll
    for (int w = 0; w < 64; ++w) {
        float e = ls1[w * 32 + i] + ls2[w * 32 + j];
        e = e > 0.f ? e : ALPHA * e;
        sum += __expf(e);
    }
    ws[WS_DEN + nh * 1024 + tid] = 1.0f / sum;
}

__device__ __forceinline__ float elu(float x) { return x > 0.f ? x : expm1f(x); }

// per site (n,h,w): Wh[j',f]; at[i][j']=exp(lrelu(s1[i]+s2[j']))*rden; M[j'][j]=sum_i adj[i][j]*at[i][j'];
// O[f][j]=sum_j' Wh[j'][f]*M[j'][j]; write elu(O) to scrambled location
__global__ __launch_bounds__(256) void k3_main(const float* __restrict__ hin,
    const float* __restrict__ W_map, const float* __restrict__ b_map,
    const float* __restrict__ ws, float* __restrict__ out)
{
    __shared__ float ht[1024];    // [t][v]
    __shared__ float wm[1024];    // [t][f]
    __shared__ float adjs[1024];  // [i][j]
    __shared__ float whs[1024];   // [j'][f]
    __shared__ float ats[1024];   // [i][j']
    __shared__ float Ms[1024];    // [j'][j]
    __shared__ float s1v[32], s2v[32];
    int tid = threadIdx.x;
    long site = blockIdx.x;           // (n*64+h)*64 + w
    int w = (int)(site & 63);
    long nh = site >> 6;
    int hh = (int)(nh & 63);
    int n = (int)(nh >> 6);

    ((float4*)ht)[tid]   = ((const float4*)(hin + site * 1024))[tid];
    ((float4*)wm)[tid]   = ((const float4*)W_map)[tid];
    ((float4*)adjs)[tid] = ((const float4*)(ws + WS_ADJ))[tid];
    if (tid < 32) s1v[tid] = ws[WS_S1 + site * 32 + tid];
    else if (tid < 64) s2v[tid - 32] = ws[WS_S2 + site * 32 + (tid - 32)];
    __syncthreads();

    // Wh[j][f] = sum_t ht[t][j]*wm[t][f] + b[f]
    {
        int j = tid >> 3, fg = (tid & 7) * 4;
        float a0 = b_map[fg], a1 = b_map[fg + 1], a2 = b_map[fg + 2], a3 = b_map[fg + 3];
#pragma unroll
        for (int t = 0; t < 32; ++t) {
            float x = ht[t * 32 + j];
            a0 = fmaf(x, wm[t * 32 + fg], a0);
            a1 = fmaf(x, wm[t * 32 + fg + 1], a1);
            a2 = fmaf(x, wm[t * 32 + fg + 2], a2);
            a3 = fmaf(x, wm[t * 32 + fg + 3], a3);
        }
        whs[j * 32 + fg] = a0; whs[j * 32 + fg + 1] = a1;
        whs[j * 32 + fg + 2] = a2; whs[j * 32 + fg + 3] = a3;
    }
    // attn numerators * rden
    {
        float4 rd = ((const float4*)(ws + WS_DEN + nh * 1024))[tid];
        int p = tid * 4;
        int i = p >> 5, jp = p & 31;
        float si = s1v[i];
        float e0 = si + s2v[jp], e1 = si + s2v[jp + 1], e2 = si + s2v[jp + 2], e3 = si + s2v[jp + 3];
        e0 = e0 > 0.f ? e0 : ALPHA * e0;  e1 = e1 > 0.f ? e1 : ALPHA * e1;
        e2 = e2 > 0.f ? e2 : ALPHA * e2;  e3 = e3 > 0.f ? e3 : ALPHA * e3;
        ats[p] = __expf(e0) * rd.x; ats[p + 1] = __expf(e1) * rd.y;
        ats[p + 2] = __expf(e2) * rd.z; ats[p + 3] = __expf(e3) * rd.w;
    }
    __syncthreads();

    // M[j'][j] = sum_i adj[i][j] * at[i][j']
    {
        int jp = tid >> 3, jg = (tid & 7) * 4;
        float m0 = 0.f, m1 = 0.f, m2 = 0.f, m3 = 0.f;
#pragma unroll
        for (int i = 0; i < 32; ++i) {
            float x = ats[i * 32 + jp];
            m0 = fmaf(x, adjs[i * 32 + jg], m0);
            m1 = fmaf(x, adjs[i * 32 + jg + 1], m1);
            m2 = fmaf(x, adjs[i * 32 + jg + 2], m2);
            m3 = fmaf(x, adjs[i * 32 + jg + 3], m3);
        }
        Ms[jp * 32 + jg] = m0; Ms[jp * 32 + jg + 1] = m1;
        Ms[jp * 32 + jg + 2] = m2; Ms[jp * 32 + jg + 3] = m3;
    }
    __syncthreads();

    // O[f][j] = sum_j' whs[j'][f] * Ms[j'][j]; elu; scrambled write
    {
        int f = tid >> 3, jg = (tid & 7) * 4;
        float o0 = 0.f, o1 = 0.f, o2 = 0.f, o3 = 0.f;
#pragma unroll
        for (int jp = 0; jp < 32; ++jp) {
            float x = whs[jp * 32 + f];
            o0 = fmaf(x, Ms[jp * 32 + jg], o0);
            o1 = fmaf(x, Ms[jp * 32 + jg + 1], o1);
            o2 = fmaf(x, Ms[jp * 32 + jg + 2], o2);
            o3 = fmaf(x, Ms[jp * 32 + jg + 3], o3);
        }
        int w3 = f * 2 + (hh >> 5);
        int f3 = hh & 31;
        float4 r;
        r.x = elu(o0); r.y = elu(o1); r.z = elu(o2); r.w = elu(o3);
        *(float4*)(out + ((((long)n * 64 + w) * 64 + w3) * 32 + f3) * 32 + jg) = r;
    }
}

extern "C" void kernel_launch(void* const* d_in, const int* in_sizes, int n_in,
                              void* d_out, int out_size, void* d_ws, size_t ws_size,
                              hipStream_t stream) {
    (void)in_sizes; (void)n_in; (void)out_size; (void)ws_size;
    const float* hin    = (const float*)d_in[0];
    const float* W_map  = (const float*)d_in[1];
    const float* b_map  = (const float*)d_in[2];
    const float* a_attn = (const float*)d_in[3];
    const float* B_adj  = (const float*)d_in[4];
    float* out = (float*)d_out;
    float* ws  = (float*)d_ws;

    hipLaunchKernelGGL(k0_prep,   dim3(1),     dim3(1024), 0, stream, W_map, b_map, a_attn, B_adj, ws);
    hipLaunchKernelGGL(k1_scores, dim3(4096),  dim3(256),  0, stream, hin, ws);
    hipLaunchKernelGGL(k2_denom,  dim3(512),   dim3(1024), 0, stream, ws);
    hipLaunchKernelGGL(k3_main,   dim3(32768), dim3(256),  0, stream, hin, W_map, b_map, ws, out);
}